// Round 2
// baseline (127.393 us; speedup 1.0000x reference)
//
#include <hip/hip_runtime.h>
#include <math.h>

#define WW 512
#define CPB 16    // columns per block
#define SEGS 64   // row segments per column
#define SEG 8     // rows per segment
#define NBLK 64   // 2 images * 32 column-groups

// Block = (image, 16-column group), 1024 threads = 16 cols x 64 segments.
// Per-column 1D nearest-False distance (both phases) via segmented scans;
// carry composition: true_d[t] = min(local_d[t] (INF-seeded), carry + t + 1).
// d = sqrt((g^2 + (g&1))/2) reproduces the reference column-envelope exactly
// (all integers < 2^24 -> fp32-exact); all-True column => d = 1024.
__global__ __launch_bounds__(1024) void morph_main(
    const float* __restrict__ img, const float* __restrict__ msk,
    const float* __restrict__ tgt, double* __restrict__ partials,
    unsigned int* __restrict__ counter, float* __restrict__ out)
{
  __shared__ unsigned short cF_f[SEGS][CPB], cF_b[SEGS][CPB];
  __shared__ unsigned short cB_f[SEGS][CPB], cB_b[SEGS][CPB];
  __shared__ unsigned short Xf[SEGS][CPB], Xb[SEGS][CPB];
  __shared__ unsigned short Yf[SEGS][CPB], Yb[SEGS][CPB];
  __shared__ double red[16][4];

  const int tid = threadIdx.x;
  const int blk = blockIdx.x;
  const float* __restrict__ src = (blk >= 32) ? tgt : img;
  const int c0 = (blk & 31) * CPB;
  const int c = tid & (CPB - 1);
  const int s = tid >> 4;            // segment 0..63
  const int col = c0 + c;
  const int rowbase = s * SEG;

  // ---- pass 1: load, binarize, local INF-seeded scans (both directions) ----
  unsigned int bbits = 0, mbits = 0;
#pragma unroll
  for (int t = 0; t < SEG; ++t) {
    const int idx = (rowbase + t) * WW + col;
    bbits |= (unsigned)(src[idx] > 0.22f) << t;
    mbits |= (unsigned)(msk[idx] > 0.5f) << t;
  }
  unsigned int fwl[SEG], bwl[SEG];
  int df = 4096, db = 4096;          // local-INF seed (> max carry 1536 + SEG)
#pragma unroll
  for (int t = 0; t < SEG; ++t) {
    const int b = (bbits >> t) & 1;
    df = b ? df + 1 : 0;             // fg: dist to nearest False above
    db = b ? 0 : db + 1;             // bg: dist to nearest True above
    fwl[t] = (unsigned)df | ((unsigned)db << 16);
  }
  int uf = 4096, ub = 4096;
#pragma unroll
  for (int t = SEG - 1; t >= 0; --t) {
    const int b = (bbits >> t) & 1;
    uf = b ? uf + 1 : 0;
    ub = b ? 0 : ub + 1;
    bwl[t] = (unsigned)uf | ((unsigned)ub << 16);
  }
  cF_f[s][c] = (unsigned short)df; cF_b[s][c] = (unsigned short)db;
  cB_f[s][c] = (unsigned short)uf; cB_b[s][c] = (unsigned short)ub;
  __syncthreads();

  // ---- carry prefix across 64 segments: 64 threads = 4 scan-types x 16 cols
  if (tid < 64) {
    const int cc = tid & 15;
    const int ty = tid >> 4;
    if (ty == 0) {
      int x = 1024;                  // reference carry seed INF = H+W
      for (int ss = 0; ss < SEGS; ++ss) { Xf[ss][cc] = (unsigned short)x; x = min((int)cF_f[ss][cc], x + SEG); }
    } else if (ty == 1) {
      int x = 1024;
      for (int ss = 0; ss < SEGS; ++ss) { Xb[ss][cc] = (unsigned short)x; x = min((int)cF_b[ss][cc], x + SEG); }
    } else if (ty == 2) {
      int y = 1024;
      for (int ss = SEGS - 1; ss >= 0; --ss) { Yf[ss][cc] = (unsigned short)y; y = min((int)cB_f[ss][cc], y + SEG); }
    } else {
      int y = 1024;
      for (int ss = SEGS - 1; ss >= 0; --ss) { Yb[ss][cc] = (unsigned short)y; y = min((int)cB_b[ss][cc], y + SEG); }
    }
  }
  __syncthreads();

  // ---- pass 2: apply carries, d, masked accumulation (doubles) ----
  const int xf = Xf[s][c], xb = Xb[s][c], yf = Yf[s][c], yb = Yb[s][c];
  double sum_f = 0.0, sum_b = 0.0;
  int cnt_f = 0, cnt_b = 0;
#pragma unroll
  for (int t = 0; t < SEG; ++t) {
    const int b = (bbits >> t) & 1;
    const int m = (mbits >> t) & 1;
    int gf = min(min((int)(fwl[t] & 0xffffu), xf + t + 1),
                 min((int)(bwl[t] & 0xffffu), yf + (SEG - t)));
    int gb = min(min((int)(fwl[t] >> 16), xb + t + 1),
                 min((int)(bwl[t] >> 16), yb + (SEG - t)));
    gf = min(gf, 1024);
    gb = min(gb, 1024);
    const float dfv = (gf >= 1024) ? 1024.0f
                                   : sqrtf((float)(gf * gf + (gf & 1)) * 0.5f);
    const float dbv = (gb >= 1024) ? 1024.0f
                                   : sqrtf((float)(gb * gb + (gb & 1)) * 0.5f);
    const int self = b & m;
    const int selb = (b ^ 1) & m;
    sum_f += self ? (double)dfv : 0.0;
    sum_b += selb ? (double)dbv : 0.0;
    cnt_f += self;
    cnt_b += selb;
  }

  // ---- block reduction: wave shuffle, then LDS across 16 waves ----
#pragma unroll
  for (int off = 32; off > 0; off >>= 1) {
    sum_f += __shfl_down(sum_f, off);
    sum_b += __shfl_down(sum_b, off);
    cnt_f += __shfl_down(cnt_f, off);
    cnt_b += __shfl_down(cnt_b, off);
  }
  const int wv = tid >> 6;
  if ((tid & 63) == 0) {
    red[wv][0] = sum_f; red[wv][1] = sum_b;
    red[wv][2] = (double)cnt_f; red[wv][3] = (double)cnt_b;
  }
  __syncthreads();

  // ---- partials + last-block finalize (saves the second launch) ----
  if (tid == 0) {
    double a = 0.0, bs = 0.0, cf = 0.0, cb = 0.0;
    for (int w = 0; w < 16; ++w) {
      a += red[w][0]; bs += red[w][1]; cf += red[w][2]; cb += red[w][3];
    }
    partials[blk * 4 + 0] = a;
    partials[blk * 4 + 1] = bs;
    partials[blk * 4 + 2] = cf;
    partials[blk * 4 + 3] = cb;
    __threadfence();                       // agent-scope release (L2 writeback)
    const unsigned int old = atomicAdd(counter, 1u);
    if (old == NBLK - 1) {                 // I'm the last block
      __threadfence();                     // agent-scope acquire (L2 inval)
      const volatile double* p = partials;
      double sAf = 0, sAb = 0, cAf = 0, cAb = 0;
      double sBf = 0, sBb = 0, cBf = 0, cBb = 0;
      for (int k = 0; k < 32; ++k) {
        sAf += p[k * 4 + 0]; sAb += p[k * 4 + 1];
        cAf += p[k * 4 + 2]; cAb += p[k * 4 + 3];
      }
      for (int k = 32; k < 64; ++k) {
        sBf += p[k * 4 + 0]; sBb += p[k * 4 + 1];
        cBf += p[k * 4 + 2]; cBb += p[k * 4 + 3];
      }
      const double tl = 2.0 * 10.5 * sAf / fmax(cAf, 1.0);
      const double th = 2.0 * 10.5 * sBf / fmax(cBf, 1.0);
      const double sl = 2.0 * 10.5 * sAb / fmax(cAb, 1.0);
      const double sh = 2.0 * 10.5 * sBb / fmax(cBb, 1.0);
      double l1 = (tl - 48.7578) / 5.2874 - (th - 48.7578) / 5.2874;
      l1 *= l1;
      double l7 = (sl - 156.729) / 46.1809 - (sh - 156.729) / 46.1809;
      l7 *= l7;
      out[0] = (float)(0.5 * (l1 + l7));
    }
  }
}

extern "C" void kernel_launch(void* const* d_in, const int* in_sizes, int n_in,
                              void* d_out, int out_size, void* d_ws, size_t ws_size,
                              hipStream_t stream) {
  const float* img = (const float*)d_in[0];
  const float* msk = (const float*)d_in[1];
  const float* tgt = (const float*)d_in[2];
  double* partials = (double*)d_ws;                       // 64 blocks * 4 doubles
  unsigned int* counter = (unsigned int*)((char*)d_ws + NBLK * 4 * sizeof(double));
  // Counter must start at 0 on every replay (ws is poisoned 0xAA); a memset
  // node inside the captured graph re-zeros it on each replay.
  hipMemsetAsync(counter, 0, sizeof(unsigned int), stream);
  morph_main<<<NBLK, 1024, 0, stream>>>(img, msk, tgt, partials, counter,
                                        (float*)d_out);
}

// Round 3
// 77.684 us; speedup vs baseline: 1.6399x; 1.6399x over previous
//
#include <hip/hip_runtime.h>
#include <math.h>

#define WW 512
#define CPB 4     // columns per block
#define SEGS 64   // row segments per column
#define SEG 8     // rows per segment
#define NBLK 256  // 2 images * 128 column-groups

// Block = (image, 4-column group), 256 threads = 4 cols x 64 segments.
// Per-column 1D nearest-False distance (both phases) via segmented scans;
// carry composition: true_d[t] = min(local_d[t] (INF-seeded), carry + t + 1).
// d = sqrt((g^2 + (g&1))/2) reproduces the reference column-envelope exactly
// (all integers < 2^24 -> fp32-exact); all-True column => d = 1024.
// Finalize fused via last-block pattern with PARALLEL volatile loads
// (R2's 72us tail was ONE thread doing 256 serialized volatile loads).
__global__ __launch_bounds__(256) void morph_main(
    const float* __restrict__ img, const float* __restrict__ msk,
    const float* __restrict__ tgt, double* __restrict__ partials,
    unsigned int* __restrict__ counter, float* __restrict__ out)
{
  __shared__ unsigned short cF_f[SEGS][CPB], cF_b[SEGS][CPB];
  __shared__ unsigned short cB_f[SEGS][CPB], cB_b[SEGS][CPB];
  __shared__ unsigned short Xf[SEGS][CPB], Xb[SEGS][CPB];
  __shared__ unsigned short Yf[SEGS][CPB], Yb[SEGS][CPB];
  __shared__ double red[4][8];
  __shared__ int flag;

  const int tid = threadIdx.x;
  const int blk = blockIdx.x;
  const float* __restrict__ src = (blk >= NBLK / 2) ? tgt : img;
  const int c0 = (blk & 127) * CPB;
  const int c = tid & (CPB - 1);
  const int s = tid >> 2;            // segment 0..63
  const int col = c0 + c;
  const int rowbase = s * SEG;

  // ---- pass 1: load, binarize, local INF-seeded scans (both directions) ----
  unsigned int bbits = 0, mbits = 0;
#pragma unroll
  for (int t = 0; t < SEG; ++t) {
    const int idx = (rowbase + t) * WW + col;
    bbits |= (unsigned)(src[idx] > 0.22f) << t;
    mbits |= (unsigned)(msk[idx] > 0.5f) << t;
  }
  unsigned int fwl[SEG], bwl[SEG];
  int df = 4096, db = 4096;          // local-INF seed (> max carry 4104? no:
                                     // carries enter via min at pass 2, 4096
                                     // only needs to exceed any true distance)
#pragma unroll
  for (int t = 0; t < SEG; ++t) {
    const int b = (bbits >> t) & 1;
    df = b ? df + 1 : 0;             // fg: dist to nearest False above
    db = b ? 0 : db + 1;             // bg: dist to nearest True above
    fwl[t] = (unsigned)df | ((unsigned)db << 16);
  }
  int uf = 4096, ub = 4096;
#pragma unroll
  for (int t = SEG - 1; t >= 0; --t) {
    const int b = (bbits >> t) & 1;
    uf = b ? uf + 1 : 0;
    ub = b ? 0 : ub + 1;
    bwl[t] = (unsigned)uf | ((unsigned)ub << 16);
  }
  cF_f[s][c] = (unsigned short)df; cF_b[s][c] = (unsigned short)db;
  cB_f[s][c] = (unsigned short)uf; cB_b[s][c] = (unsigned short)ub;
  __syncthreads();

  // ---- carry prefix across 64 segments: 16 threads = 4 scan-types x 4 cols
  if (tid < 16) {
    const int cc = tid & 3;
    const int ty = tid >> 2;
    if (ty == 0) {
      int x = 1024;                  // reference carry seed INF = H+W
      for (int ss = 0; ss < SEGS; ++ss) { Xf[ss][cc] = (unsigned short)x; x = min((int)cF_f[ss][cc], x + SEG); }
    } else if (ty == 1) {
      int x = 1024;
      for (int ss = 0; ss < SEGS; ++ss) { Xb[ss][cc] = (unsigned short)x; x = min((int)cF_b[ss][cc], x + SEG); }
    } else if (ty == 2) {
      int y = 1024;
      for (int ss = SEGS - 1; ss >= 0; --ss) { Yf[ss][cc] = (unsigned short)y; y = min((int)cB_f[ss][cc], y + SEG); }
    } else {
      int y = 1024;
      for (int ss = SEGS - 1; ss >= 0; --ss) { Yb[ss][cc] = (unsigned short)y; y = min((int)cB_b[ss][cc], y + SEG); }
    }
  }
  __syncthreads();

  // ---- pass 2: apply carries, d, masked accumulation (doubles) ----
  const int xf = Xf[s][c], xb = Xb[s][c], yf = Yf[s][c], yb = Yb[s][c];
  double sum_f = 0.0, sum_b = 0.0;
  int cnt_f = 0, cnt_b = 0;
#pragma unroll
  for (int t = 0; t < SEG; ++t) {
    const int b = (bbits >> t) & 1;
    const int m = (mbits >> t) & 1;
    int gf = min(min((int)(fwl[t] & 0xffffu), xf + t + 1),
                 min((int)(bwl[t] & 0xffffu), yf + (SEG - t)));
    int gb = min(min((int)(fwl[t] >> 16), xb + t + 1),
                 min((int)(bwl[t] >> 16), yb + (SEG - t)));
    gf = min(gf, 1024);
    gb = min(gb, 1024);
    const float dfv = (gf >= 1024) ? 1024.0f
                                   : sqrtf((float)(gf * gf + (gf & 1)) * 0.5f);
    const float dbv = (gb >= 1024) ? 1024.0f
                                   : sqrtf((float)(gb * gb + (gb & 1)) * 0.5f);
    const int self = b & m;
    const int selb = (b ^ 1) & m;
    sum_f += self ? (double)dfv : 0.0;
    sum_b += selb ? (double)dbv : 0.0;
    cnt_f += self;
    cnt_b += selb;
  }

  // ---- block reduction: wave shuffle, then LDS across 4 waves ----
#pragma unroll
  for (int off = 32; off > 0; off >>= 1) {
    sum_f += __shfl_down(sum_f, off);
    sum_b += __shfl_down(sum_b, off);
    cnt_f += __shfl_down(cnt_f, off);
    cnt_b += __shfl_down(cnt_b, off);
  }
  const int wv = tid >> 6;
  if ((tid & 63) == 0) {
    red[wv][0] = sum_f; red[wv][1] = sum_b;
    red[wv][2] = (double)cnt_f; red[wv][3] = (double)cnt_b;
  }
  __syncthreads();

  if (tid == 0) {
    double a = 0.0, bs = 0.0, cf = 0.0, cb = 0.0;
    for (int w = 0; w < 4; ++w) {
      a += red[w][0]; bs += red[w][1]; cf += red[w][2]; cb += red[w][3];
    }
    partials[blk * 4 + 0] = a;
    partials[blk * 4 + 1] = bs;
    partials[blk * 4 + 2] = cf;
    partials[blk * 4 + 3] = cb;
    __threadfence();                       // device-scope release
    const unsigned int old = atomicAdd(counter, 1u);
    flag = (old == NBLK - 1);              // am I the last block?
  }
  __syncthreads();
  if (!flag) return;

  // ---- last block only: PARALLEL finalize (thread tid <-> block tid) ----
  __threadfence();                         // device-scope acquire
  const volatile double* p = partials;
  const double t0 = p[tid * 4 + 0];
  const double t1 = p[tid * 4 + 1];
  const double t2 = p[tid * 4 + 2];
  const double t3 = p[tid * 4 + 3];
  const bool isB = (tid >= NBLK / 2);      // image 1 = target
  double a0 = isB ? 0.0 : t0, a1 = isB ? 0.0 : t1;
  double a2 = isB ? 0.0 : t2, a3 = isB ? 0.0 : t3;
  double b0 = isB ? t0 : 0.0, b1 = isB ? t1 : 0.0;
  double b2 = isB ? t2 : 0.0, b3 = isB ? t3 : 0.0;
#pragma unroll
  for (int off = 32; off > 0; off >>= 1) {
    a0 += __shfl_down(a0, off); a1 += __shfl_down(a1, off);
    a2 += __shfl_down(a2, off); a3 += __shfl_down(a3, off);
    b0 += __shfl_down(b0, off); b1 += __shfl_down(b1, off);
    b2 += __shfl_down(b2, off); b3 += __shfl_down(b3, off);
  }
  __syncthreads();                         // red[] reuse barrier
  if ((tid & 63) == 0) {
    red[wv][0] = a0; red[wv][1] = a1; red[wv][2] = a2; red[wv][3] = a3;
    red[wv][4] = b0; red[wv][5] = b1; red[wv][6] = b2; red[wv][7] = b3;
  }
  __syncthreads();
  if (tid == 0) {
    double sAf = 0, sAb = 0, cAf = 0, cAb = 0;
    double sBf = 0, sBb = 0, cBf = 0, cBb = 0;
    for (int w = 0; w < 4; ++w) {
      sAf += red[w][0]; sAb += red[w][1]; cAf += red[w][2]; cAb += red[w][3];
      sBf += red[w][4]; sBb += red[w][5]; cBf += red[w][6]; cBb += red[w][7];
    }
    const double tl = 2.0 * 10.5 * sAf / fmax(cAf, 1.0);  // thicknessl (img)
    const double th = 2.0 * 10.5 * sBf / fmax(cBf, 1.0);  // thicknessh (tgt)
    const double sl = 2.0 * 10.5 * sAb / fmax(cAb, 1.0);  // separationl
    const double sh = 2.0 * 10.5 * sBb / fmax(cBb, 1.0);  // separationh
    double l1 = (tl - 48.7578) / 5.2874 - (th - 48.7578) / 5.2874;
    l1 *= l1;
    double l7 = (sl - 156.729) / 46.1809 - (sh - 156.729) / 46.1809;
    l7 *= l7;
    out[0] = (float)(0.5 * (l1 + l7));
  }
}

extern "C" void kernel_launch(void* const* d_in, const int* in_sizes, int n_in,
                              void* d_out, int out_size, void* d_ws, size_t ws_size,
                              hipStream_t stream) {
  const float* img = (const float*)d_in[0];
  const float* msk = (const float*)d_in[1];
  const float* tgt = (const float*)d_in[2];
  double* partials = (double*)d_ws;                       // 256 blocks * 4 doubles
  unsigned int* counter = (unsigned int*)((char*)d_ws + NBLK * 4 * sizeof(double));
  // Counter must start at 0 on every replay (ws is poisoned 0xAA); a memset
  // node inside the captured graph re-zeros it on each replay.
  hipMemsetAsync(counter, 0, sizeof(unsigned int), stream);
  morph_main<<<NBLK, 256, 0, stream>>>(img, msk, tgt, partials, counter,
                                       (float*)d_out);
}